// Round 7
// baseline (217.409 us; speedup 1.0000x reference)
//
#include <hip/hip_runtime.h>
#include <cmath>

#define EPSF 1e-7f

constexpr int B_ = 4, S_ = 1024, E_ = 1024, H_ = 16, D_ = 64;
constexpr int BS_ = B_ * S_;   // 4096 rows per matrix

typedef __attribute__((ext_vector_type(8))) short bf16x8;
typedef __attribute__((ext_vector_type(4))) float f32x4;

__device__ inline unsigned int fbits(float f) { union { float f; unsigned int u; } x; x.f = f; return x.u; }
__device__ inline float ubits(unsigned int u) { union { unsigned int u; float f; } x; x.u = u; return x.f; }

__device__ inline unsigned short f2bf(float f) {
  unsigned int u = fbits(f);
  unsigned int r = u + 0x7fffu + ((u >> 16) & 1u);   // RNE
  return (unsigned short)(r >> 16);
}
__device__ inline float bf2f(unsigned short h) { return ubits(((unsigned int)h) << 16); }
__device__ inline float fastrcp(float x) { return __builtin_amdgcn_rcpf(x); }
__device__ inline float fastsqrt(float x) { return __builtin_amdgcn_sqrtf(x); }

// async global -> LDS DMA, 16B/lane; LDS dest = wave-uniform base + lane*16
__device__ __forceinline__ void async_ld16(const unsigned short* g, unsigned short* l) {
  __builtin_amdgcn_global_load_lds(
      (const __attribute__((address_space(1))) unsigned int*)g,
      (__attribute__((address_space(3))) unsigned int*)l, 16, 0, 0);
}

// pack two f32 -> one u32 of 2 bf16 (RNE), single VALU op
__device__ __forceinline__ unsigned int cvt_pk_bf16(float lo, float hi) {
  unsigned int r;
  asm("v_cvt_pk_bf16_f32 %0, %1, %2" : "=v"(r) : "v"(lo), "v"(hi));
  return r;
}
// a.rows{2,3} <-> b.rows{0,1}
__device__ __forceinline__ void permlane32_swap(unsigned int &a, unsigned int &b) {
  asm("v_permlane32_swap_b32 %0, %1" : "+v"(a), "+v"(b));
}
// a.rows{1,3} <-> b.rows{0,2}
__device__ __forceinline__ void permlane16_swap(unsigned int &a, unsigned int &b) {
  asm("v_permlane16_swap_b32 %0, %1" : "+v"(a), "+v"(b));
}

// ---------------- kernel 1: fused prep ----------------
// blocks [0, 3*BS/4): x -> RNE bf16 + per-row lambda, one WAVE per row (no LDS/barrier)
// blocks [3*BS/4, +768): transpose z -> RNE bf16 BT[n][k] + partial column sums (zsplit)
__global__ __launch_bounds__(256) void prep_kernel(
    const float* __restrict__ xq, const float* __restrict__ xk,
    const float* __restrict__ xv, unsigned short* __restrict__ Xbf,
    float* __restrict__ lamRow,
    const float* __restrict__ zq, const float* __restrict__ zk, const float* __restrict__ zv,
    unsigned short* __restrict__ BhiT, float* __restrict__ Zpart) {
  const int bid = blockIdx.x;
  const int tid = threadIdx.x;
  if (bid < 3 * BS_ / 4) {
    // ---- xsplit: wave-per-row ----
    const int wid = tid >> 6, lane = tid & 63;
    const int row = bid * 4 + wid;
    const float* x = (row < BS_) ? xq : (row < 2 * BS_ ? xk : xv);
    const int r = row & (BS_ - 1);
    const float4* src = (const float4*)(x + (size_t)r * E_);
    float4 v[4];
    #pragma unroll
    for (int j = 0; j < 4; j++) v[j] = src[lane + 64 * j];
    float s = 0.f;
    #pragma unroll
    for (int j = 0; j < 4; j++)
      s += v[j].x * v[j].x + v[j].y * v[j].y + v[j].z * v[j].z + v[j].w * v[j].w;
    #pragma unroll
    for (int m = 1; m < 64; m <<= 1) s += __shfl_xor(s, m, 64);
    uint2* dst = (uint2*)(Xbf + (size_t)row * E_);
    #pragma unroll
    for (int j = 0; j < 4; j++) {
      uint2 p;
      p.x = (unsigned int)f2bf(v[j].x) | ((unsigned int)f2bf(v[j].y) << 16);
      p.y = (unsigned int)f2bf(v[j].z) | ((unsigned int)f2bf(v[j].w) << 16);
      dst[lane + 64 * j] = p;
    }
    if (lane == 0) lamRow[row] = 2.0f / fmaxf(1.0f - s, EPSF);
    return;
  }
  // ---- zsplit ----
  const int lid = bid - 3 * BS_ / 4;           // 0..767
  const int mat = lid >> 8;                    // 0..2
  const int rem = lid & 255;
  const int ky = rem >> 4, nx = rem & 15;
  const float* z = mat == 0 ? zq : (mat == 1 ? zk : zv);
  const int k0 = ky * 64, n0 = nx * 64;
  __shared__ float t[64][65];
  __shared__ float sred[64][4];
  {
    int kr = tid >> 4, nc = (tid & 15) * 4;
    #pragma unroll
    for (int i = 0; i < 4; i++) {
      float4 vv = *(const float4*)(z + (size_t)(k0 + kr + i * 16) * E_ + n0 + nc);
      t[kr + i * 16][nc + 0] = vv.x;
      t[kr + i * 16][nc + 1] = vv.y;
      t[kr + i * 16][nc + 2] = vv.z;
      t[kr + i * 16][nc + 3] = vv.w;
    }
  }
  __syncthreads();
  int nr = tid >> 2, kc = (tid & 3) * 16;
  unsigned int ph[8];
  float ss = 0.f;
  #pragma unroll
  for (int p = 0; p < 8; p++) {
    float x0 = t[kc + 2 * p][nr], x1 = t[kc + 2 * p + 1][nr];
    ph[p] = (unsigned int)f2bf(x0) | ((unsigned int)f2bf(x1) << 16);
    ss += x0 * x0 + x1 * x1;
  }
  size_t off = (size_t)mat * E_ * E_ + (size_t)(n0 + nr) * E_ + k0 + kc;
  uint4* dh = (uint4*)(BhiT + off);
  dh[0] = make_uint4(ph[0], ph[1], ph[2], ph[3]);
  dh[1] = make_uint4(ph[4], ph[5], ph[6], ph[7]);
  sred[nr][tid & 3] = ss;
  __syncthreads();
  if (tid < 64) {
    float v = sred[tid][0] + sred[tid][1] + sred[tid][2] + sred[tid][3];
    Zpart[(size_t)(mat * 16 + ky) * E_ + n0 + tid] = v;
  }
}

// ---------------- kernel 3: 1-term bf16 MFMA GEMM, (mat,m0)-pairs per XCD, zstat folded ----------------
// Double-buffered staging with depth-1 prefetch + ONE raw s_barrier per K-step:
// issue next tile's global_load_lds at iteration top, compute current tile (32 MFMA/wave covers the
// load latency), then s_waitcnt vmcnt(0) + s_barrier.  (Old structure: 2 barriers/iter with naked
// load latency between them — same disease attention had, same cure, -33% there.)
__global__ __launch_bounds__(256, 2) void hlinear_mfma_kernel(
    const unsigned short* __restrict__ Xbf,
    const unsigned short* __restrict__ BhiT,
    const float* __restrict__ lamRow, const float* __restrict__ Zpart,
    const float* __restrict__ bq, const float* __restrict__ bk, const float* __restrict__ bv,
    unsigned short* __restrict__ Wbf) {
  const int fid = blockIdx.x;
  const int xcd = fid & 7, j = fid >> 3;
  const int n0 = (j & 7) * 128;
  const int gp = xcd * 12 + (j >> 3);   // 0..95
  const int mat = gp >> 5;
  const int m0 = (gp & 31) * 128;

  const unsigned short* xa = Xbf + (size_t)mat * BS_ * E_;
  const unsigned short* bh = BhiT + (size_t)mat * E_ * E_;

  __shared__ unsigned short LDSU[2][16384];   // [buf][As 8192 | Bh 8192] shorts; epilogue reuses buf0
  __shared__ float chznS[128], shS[128], tznS[128];

  const int tid = threadIdx.x;
  const int wid = tid >> 6, lane = tid & 63, quad = lane >> 4, l16 = lane & 15;
  const int wm = (wid >> 1) * 64, wn = (wid & 1) * 64;

  const int lrow = lane >> 3;
  const int lcs = ((lane & 7) ^ lrow) * 8;
  const int xsw = (l16 & 7);

  // stage tile 0 into buf 0 (latency overlaps the stats prologue below)
  #pragma unroll
  for (int c2 = 0; c2 < 4; c2++) {
    const int c = wid * 4 + c2;
    const int grow = c * 8 + lrow;
    async_ld16(xa + (size_t)(m0 + grow) * E_ + lcs, &LDSU[0][c * 512]);
    async_ld16(bh + (size_t)(n0 + grow) * E_ + lcs, &LDSU[0][8192 + c * 512]);
  }

  // ---- prologue: column stats (zstat fold) ----
  if (tid < 128) {
    const int col = n0 + tid;
    float s = 0.f;
    #pragma unroll
    for (int ky = 0; ky < 16; ky++)
      s += Zpart[(size_t)(mat * 16 + ky) * E_ + col];
    float zn = fmaxf(sqrtf(s), 1e-15f);
    const float* bb = (mat == 0) ? bq : ((mat == 1) ? bk : bv);
    float rb = bb[col];
    chznS[tid] = coshf(2.f * rb) / zn;
    shS[tid] = sinhf(2.f * rb);
    tznS[tid] = 2.f * zn;
  }

  f32x4 acc[4][4];
  #pragma unroll
  for (int i = 0; i < 4; i++)
    #pragma unroll
    for (int jj = 0; jj < 4; jj++) acc[i][jj] = (f32x4){0.f, 0.f, 0.f, 0.f};

  // prologue drain: tile 0 + stats LDS writes complete
  asm volatile("s_waitcnt vmcnt(0) lgkmcnt(0)" ::: "memory");
  __builtin_amdgcn_s_barrier();

  const int NTk = E_ / 64;   // 16
  int buf = 0;
  #pragma unroll 1
  for (int kt = 0; kt < NTk; ++kt) {
    if (kt + 1 < NTk) {   // depth-1 prefetch into the other buffer; lands during this compute
      const int kb = (kt + 1) * 64 + lcs;
      #pragma unroll
      for (int c2 = 0; c2 < 4; c2++) {
        const int c = wid * 4 + c2;
        const int grow = c * 8 + lrow;
        async_ld16(xa + (size_t)(m0 + grow) * E_ + kb, &LDSU[buf ^ 1][c * 512]);
        async_ld16(bh + (size_t)(n0 + grow) * E_ + kb, &LDSU[buf ^ 1][8192 + c * 512]);
      }
    }
    const unsigned short* As = LDSU[buf];
    const unsigned short* Bh2 = LDSU[buf] + 8192;
    #pragma unroll
    for (int h = 0; h < 2; h++) {
      bf16x8 a[4];
      #pragma unroll
      for (int mt = 0; mt < 4; mt++) {
        int row = wm + mt * 16 + l16;
        a[mt] = *(const bf16x8*)&As[row * 64 + (((h * 4 + quad) ^ xsw) * 8)];
      }
      #pragma unroll
      for (int nt = 0; nt < 4; nt++) {
        int row = wn + nt * 16 + l16;
        bf16x8 bhf = *(const bf16x8*)&Bh2[row * 64 + (((h * 4 + quad) ^ xsw) * 8)];
        #pragma unroll
        for (int mt = 0; mt < 4; mt++)
          acc[mt][nt] = __builtin_amdgcn_mfma_f32_16x16x32_bf16(a[mt], bhf, acc[mt][nt], 0, 0, 0);
      }
    }
    // prefetch had the whole compute phase to land; one barrier per K-step
    asm volatile("s_waitcnt vmcnt(0)" ::: "memory");
    __builtin_amdgcn_s_barrier();
    buf ^= 1;
  }

  const float* lamP = lamRow + mat * BS_;
  float lamv[16];
  #pragma unroll
  for (int mt = 0; mt < 4; mt++)
    #pragma unroll
    for (int r = 0; r < 4; r++)
      lamv[mt * 4 + r] = lamP[m0 + wm + mt * 16 + quad * 4 + r];

  __syncthreads();
  unsigned short* epi = &LDSU[0][0] + wid * 4608;   // 64 rows x 72 shorts per wave
  #pragma unroll
  for (int nt = 0; nt < 4; nt++) {
    int ci = wn + nt * 16 + l16;
    float chzn = chznS[ci];
    float sh = shS[ci];
    float tzn = tznS[ci];
    #pragma unroll
    for (int mt = 0; mt < 4; mt++) {
      #pragma unroll
      for (int r = 0; r < 4; r++) {
        float lam = lamv[mt * 4 + r];
        float arg = fmaf(lam * acc[mt][nt][r], chzn, -(lam - 1.f) * sh);
        float sq2 = sqrtf(fmaf(arg, arg, 1.f));
        float v = tzn * __logf(arg + sq2);
        float ev = __expf(v);
        float w = 0.5f * (ev - fastrcp(ev));
        epi[(mt * 16 + quad * 4 + r) * 72 + nt * 16 + l16] = f2bf(w);
      }
    }
  }
  unsigned short* gout = Wbf + (size_t)mat * BS_ * E_ + (size_t)(m0 + wm) * E_ + n0 + wn;
  const int rrow = lane >> 3, seg = lane & 7;
  #pragma unroll
  for (int i = 0; i < 8; i++) {
    int row = i * 8 + rrow;
    uint4 val = *(const uint4*)&epi[row * 72 + seg * 8];
    *(uint4*)(gout + (size_t)row * E_ + seg * 8) = val;
  }
}

// ---------------- kernel 4: normalize + per-mat epilogues (wave-per-row) ----------------
__global__ __launch_bounds__(256) void normalize_kernel(
    const unsigned short* __restrict__ Wbf, unsigned short* __restrict__ Pbf,
    float* __restrict__ HN,
    unsigned short* __restrict__ KsG, unsigned short* __restrict__ lamMG,
    unsigned int* __restrict__ auxG) {
  const int wid = threadIdx.x >> 6, lane = threadIdx.x & 63;
  const int row = blockIdx.x * 4 + wid;          // 0 .. 3*BS-1
  const unsigned short* w = Wbf + (size_t)row * E_;
  union { uint4 q[2]; unsigned short s[16]; } in;
  in.q[0] = ((const uint4*)w)[lane * 2];
  in.q[1] = ((const uint4*)w)[lane * 2 + 1];
  float wv[16];
  float s = 0.f;
  #pragma unroll
  for (int i = 0; i < 16; i++) { wv[i] = bf2f(in.s[i]); s += wv[i] * wv[i]; }
  #pragma unroll
  for (int m = 1; m < 64; m <<= 1) s += __shfl_xor(s, m, 64);
  float t = 1.f / (1.f + sqrtf(1.f + s));
  union { uint4 q[2]; unsigned short s[16]; } out;
  float rv[16];
  float hs = 0.f;
  #pragma unroll
  for (int i = 0; i < 16; i++) {
    unsigned short p = f2bf(wv[i] * t);
    out.s[i] = p;
    rv[i] = bf2f(p);
    hs += rv[i] * rv[i];
  }
  hs += __shfl_xor(hs, 1, 64);
  hs += __shfl_xor(hs, 2, 64);                   // per-head (4-lane group) squared norm
  const int mat = row >= 2 * BS_ ? 2 : (row >= BS_ ? 1 : 0);
  const int r4 = row & (BS_ - 1);
  const int b = r4 >> 10, key = r4 & (S_ - 1);
  const int head = lane >> 2;
  const size_t bhS = ((size_t)(b * H_ + head)) * S_;
  if (mat == 0) {
    ((uint4*)(Pbf + (size_t)row * E_))[lane * 2] = out.q[0];
    ((uint4*)(Pbf + (size_t)row * E_))[lane * 2 + 1] = out.q[1];
    if ((lane & 3) == 0) HN[(size_t)r4 * H_ + head] = hs;
  } else if (mat == 1) {
    float c = fastrcp(1.f - hs);
    union { uint4 q[2]; unsigned short s[16]; } ks;
    #pragma unroll
    for (int i = 0; i < 16; i++) ks.s[i] = f2bf(rv[i] * c);
    unsigned short* dst = KsG + (bhS + key) * 64 + (lane & 3) * 16;
    ((uint4*)dst)[0] = ks.q[0];
    ((uint4*)dst)[1] = ks.q[1];
    if ((lane & 3) == 0)
      auxG[bhS + key] = (unsigned int)f2bf(c) | ((unsigned int)f2bf(c * hs) << 16);
  } else {
    float lam = 2.f / fmaxf(1.f - hs, EPSF);
    union { uint4 q[2]; unsigned short s[16]; } pv;
    #pragma unroll
    for (int i = 0; i < 16; i++) pv.s[i] = f2bf(rv[i] * lam);
    ((uint4*)(Pbf + (size_t)row * E_))[lane * 2] = pv.q[0];
    ((uint4*)(Pbf + (size_t)row * E_))[lane * 2 + 1] = pv.q[1];
    if ((lane & 3) == 0) lamMG[bhS + key] = f2bf(lam - 1.f);
  }
}

// ---------------- kernel 4b: V head-transpose (pure transpose; lambda already folded) ----------------
__global__ __launch_bounds__(256) void vtrans_kernel(
    const unsigned short* __restrict__ PvF, unsigned short* __restrict__ VtG) {
  const int st = blockIdx.x, h = blockIdx.y, b = blockIdx.z;
  __shared__ unsigned short T[64][72];
  const int tid = threadIdx.x;
  const size_t bhS = (size_t)(b * H_ + h) * S_;
  {
    int lr = tid >> 2, lc = (tid & 3) * 16;
    const uint4* src = (const uint4*)(PvF + (size_t)(b * S_ + st * 64 + lr) * E_ + h * 64 + lc);
    *(uint4*)&T[lr][lc] = src[0];
    *(uint4*)&T[lr][lc + 8] = src[1];
  }
  __syncthreads();
  int d = tid >> 2, sc = (tid & 3) * 16;
  unsigned int o[8];
  #pragma unroll
  for (int i = 0; i < 8; i++) {
    int s0 = sc + 2 * i;
    o[i] = (unsigned int)T[s0][d] | ((unsigned int)T[s0 + 1][d] << 16);
  }
  unsigned short* dst = VtG + bhS * 64 + (size_t)d * S_ + st * 64 + sc;
  ((uint4*)dst)[0] = make_uint4(o[0], o[1], o[2], o[3]);
  ((uint4*)dst)[1] = make_uint4(o[4], o[5], o[6], o[7]);
}

// ---------------- kernel 5: MFMA attention; XCD-grouped, BK=128 double-tile pipeline ----------------
// (round-5 version reverted verbatim: 512 thr / 8 waves, 16 waves/CU — the 2-q-set variant
// regressed because occupancy loss beat LDS amortization; attention is TLP/latency-bound.)
__global__ __launch_bounds__(512) void attention_kernel(
    const unsigned short* __restrict__ Pbf, const float* __restrict__ HN,
    const unsigned short* __restrict__ KsG, const unsigned short* __restrict__ VtG,
    const unsigned short* __restrict__ lamMG, const unsigned int* __restrict__ auxG,
    float* __restrict__ TV, float scale) {
  const int fid = blockIdx.x;
  const int xcd = fid & 7, slot = fid >> 3;          // slot 0..63
  const int group = xcd + 8 * (slot >> 3);           // 0..63  (= h + 16*b)
  const int qt = slot & 7;
  const int h = group & 15, b = group >> 4;

  const unsigned short* pq = Pbf;
  const float* hnq = HN;

  const int tid = threadIdx.x;
  const int wid = tid >> 6, lane = tid & 63;
  const int quad = lane >> 4, l16 = lane & 15;

  __shared__ __align__(16) unsigned short Kl[2][8192];   // 2 x (2 key-tiles x 64x64), xor-swizzled
  __shared__ __align__(16) unsigned short Vl[2][8192];   // 2 x (2 dim-tiles), xor-swizzled
  __shared__ __align__(16) unsigned short lamL[1024];
  __shared__ __align__(16) unsigned int auxL[1024];

  const size_t bhS = (size_t)(b * H_ + h) * S_;
  const int lr = lane >> 3, cch = lane & 7;
  const int xsw = l16 & 7;
  const unsigned short* kbase = KsG + bhS * 64;   // row stride 64
  const unsigned short* vbase = VtG + bhS * 64;
  const int srow = wid * 8 + lr;                  // staging row (K: key / V: dim)
  const int scc = ((cch ^ lr) * 8);               // pre-swizzled source column

  // stage super-tile 0 (key tiles 0,1) early (latency overlaps Q prep)
  async_ld16(kbase + (size_t)srow * 64 + scc, &Kl[0][wid * 512]);
  async_ld16(kbase + (size_t)(64 + srow) * 64 + scc, &Kl[0][4096 + wid * 512]);
  async_ld16(vbase + (size_t)srow * S_ + scc, &Vl[0][wid * 512]);
  async_ld16(vbase + (size_t)srow * S_ + 64 + scc, &Vl[0][4096 + wid * 512]);

  ((unsigned int*)lamL)[tid] = ((const unsigned int*)(lamMG + bhS))[tid];
  ((uint2*)auxL)[tid] = ((const uint2*)(auxG + bhS))[tid];

  const int qrow0 = qt * 128 + wid * 16;
  const size_t qgrow = ((size_t)(b * S_ + qrow0 + l16)) * E_ + h * 64;
  bf16x8 aq0r = *(const bf16x8*)(pq + qgrow + quad * 8);
  bf16x8 aq1r = *(const bf16x8*)(pq + qgrow + 32 + quad * 8);
  const float q2l = hnq[((size_t)(b * S_ + qrow0 + l16)) * H_ + h];
  const float al = 2.f * fastrcp(1.f - q2l);
  const float sc2 = -2.f * al;
  bf16x8 aq0, aq1;
  #pragma unroll
  for (int j = 0; j < 8; j++) {
    aq0[j] = (short)f2bf(bf2f((unsigned short)aq0r[j]) * sc2);
    aq1[j] = (short)f2bf(bf2f((unsigned short)aq1r[j]) * sc2);
  }
  const unsigned short ae0 = (quad == 0) ? f2bf(al * q2l) : 0;
  const unsigned short ae1 = (quad == 0) ? f2bf(al) : 0;
  const bf16x8 aex = (bf16x8){(short)ae0, (short)ae1, 0, 0, 0, 0, 0, 0};

  f32x4 accO[4];
  #pragma unroll
  for (int dt = 0; dt < 4; dt++) accO[dt] = (f32x4){0.f, 0.f, 0.f, 0.f};
  f32x4 accD = (f32x4){0.f, 0.f, 0.f, 0.f};

  // prologue drain: super-tile 0 + lam/aux all complete
  asm volatile("s_waitcnt vmcnt(0) lgkmcnt(0)" ::: "memory");
  __builtin_amdgcn_s_barrier();

  const int NIT = S_ / 128;   // 8
  int buf = 0;
  #pragma unroll 1
  for (int it = 0; it < NIT; ++it) {
    if (it + 1 < NIT) {   // stage next super-tile early; lands during this 2-tile compute
      const int kr0 = (it + 1) * 128;
      async_ld16(kbase + (size_t)(kr0 + srow) * 64 + scc, &Kl[buf ^ 1][wid * 512]);
      async_ld16(kbase + (size_t)(kr0 + 64 + srow) * 64 + scc, &Kl[buf ^ 1][4096 + wid * 512]);
      async_ld16(vbase + (size_t)srow * S_ + kr0 + scc, &Vl[buf ^ 1][wid * 512]);
      async_ld16(vbase + (size_t)srow * S_ + kr0 + 64 + scc, &Vl[buf ^ 1][4096 + wid * 512]);
    }
    #pragma unroll
    for (int half = 0; half < 2; half++) {
      const int kt = it * 2 + half;
      const unsigned short* Kb = &Kl[buf][half * 4096];
      const unsigned short* Vb = &Vl[buf][half * 4096];

      // ---- scores (swapped): per lane q=l16, key=16nt+4quad+r2; w = A - sqrt(A^2-1) ----
      unsigned int Wp[4][2];
      #pragma unroll
      for (int nt = 0; nt < 4; nt++) {
        const int krow = nt * 16 + l16;
        bf16x8 bk0 = *(const bf16x8*)&Kb[krow * 64 + ((quad ^ xsw) * 8)];
        bf16x8 bk1 = *(const bf16x8*)&Kb[krow * 64 + (((4 + quad) ^ xsw) * 8)];
        unsigned int av = (quad == 0) ? auxL[kt * 64 + krow] : 0u;
        bf16x8 bex = (bf16x8){(short)(av & 0xFFFF), (short)(av >> 16), 0, 0, 0, 0, 0, 0};
        f32x4 z = (f32x4){0.f, 0.f, 0.f, 0.f};
        f32x4 st = __builtin_amdgcn_mfma_f32_16x16x32_bf16(bex, aex, z, 0, 0, 0);
        st = __builtin_amdgcn_mfma_f32_16x16x32_bf16(bk0, aq0, st, 0, 0, 0);
        st = __builtin_amdgcn_mfma_f32_16x16x32_bf16(bk1, aq1, st, 0, 0, 0);
        float w[4];
        #pragma unroll
        for (int r2 = 0; r2 < 4; r2++) {
          float t = fmaxf(st[r2], 1e-6f);
          float A = 1.f + t;
          w[r2] = A - fastsqrt(fmaf(A, A, -1.f));
        }
        Wp[nt][0] = cvt_pk_bf16(w[0], w[1]);
        Wp[nt][1] = cvt_pk_bf16(w[2], w[3]);
      }
      // ---- redistribute scores into PV A-fragments (registers only) ----
      unsigned int x00 = Wp[0][0], y00 = Wp[1][0];
      permlane32_swap(x00, y00); permlane16_swap(x00, y00);
      unsigned int x01 = Wp[0][1], y01 = Wp[1][1];
      permlane32_swap(x01, y01); permlane16_swap(x01, y01);
      unsigned int x10 = Wp[2][0], y10 = Wp[3][0];
      permlane32_swap(x10, y10); permlane16_swap(x10, y10);
      unsigned int x11 = Wp[2][1], y11 = Wp[3][1];
      permlane32_swap(x11, y11); permlane16_swap(x11, y11);
      union { unsigned int u[4]; bf16x8 v; } ap0u, ap1u;
      ap0u.u[0] = x00; ap0u.u[1] = x01; ap0u.u[2] = y00; ap0u.u[3] = y01;
      ap1u.u[0] = x10; ap1u.u[1] = x11; ap1u.u[2] = y10; ap1u.u[3] = y11;
      const bf16x8 ap0 = ap0u.v, ap1 = ap1u.v;

      // ---- PV + dnm via K=32 MFMA ----
      #pragma unroll
      for (int dt = 0; dt < 4; dt++) {
        const int drow = dt * 16 + l16;
        bf16x8 bv0 = *(const bf16x8*)&Vb[drow * 64 + ((quad ^ xsw) * 8)];
        bf16x8 bv1 = *(const bf16x8*)&Vb[drow * 64 + (((4 + quad) ^ xsw) * 8)];
        accO[dt] = __builtin_amdgcn_mfma_f32_16x16x32_bf16(ap0, bv0, accO[dt], 0, 0, 0);
        accO[dt] = __builtin_amdgcn_mfma_f32_16x16x32_bf16(ap1, bv1, accO[dt], 0, 0, 0);
      }
      bf16x8 bl0 = *(const bf16x8*)&lamL[kt * 64 + quad * 8];        // broadcast per quad
      bf16x8 bl1 = *(const bf16x8*)&lamL[kt * 64 + 32 + quad * 8];
      accD = __builtin_amdgcn_mfma_f32_16x16x32_bf16(ap0, bl0, accD, 0, 0, 0);
      accD = __builtin_amdgcn_mfma_f32_16x16x32_bf16(ap1, bl1, accD, 0, 0, 0);
    }

    // next super-tile staged early has had the whole 2-tile compute to land
    asm volatile("s_waitcnt vmcnt(0)" ::: "memory");
    __builtin_amdgcn_s_barrier();
    buf ^= 1;
  }

  // ---- finalize: u = num/dnm; midpoint; logmap0*scale ----
  #pragma unroll
  for (int r2 = 0; r2 < 4; r2++) {
    float rdsum = fastrcp(accD[r2]);                 // dnm >= 1 (lam-1 >= 1)
    float uu[4];
    float su = 0.f;
    #pragma unroll
    for (int dt = 0; dt < 4; dt++) { uu[dt] = accO[dt][r2] * rdsum; su += uu[dt] * uu[dt]; }
    su += __shfl_xor(su, 1, 64);
    su += __shfl_xor(su, 2, 64);
    su += __shfl_xor(su, 4, 64);
    su += __shfl_xor(su, 8, 64);
    float g = fastrcp(1.f + fastsqrt(fmaxf(1.f - su, EPSF)));
    float n2 = fmaxf(su * g * g, 1e-15f);
    float n = fastsqrt(n2);
    float fac = atanhf(fminf(n, 1.f - 1e-6f)) * fastrcp(n) * g * scale;
    size_t orow = ((size_t)(b * S_ + qrow0 + quad * 4 + r2)) * E_ + h * 64 + l16;
    #pragma unroll
    for (int dt = 0; dt < 4; dt++) TV[orow + dt * 16] = fac * uu[dt];
  }
}

// ---------------- kernel 6: expmap0 per full E-row, in-place on d_out (wave-per-row) ----------------
__global__ __launch_bounds__(256) void expmap_kernel(float* __restrict__ TV) {
  const int wid = threadIdx.x >> 6, lane = threadIdx.x & 63;
  const int row = blockIdx.x * 4 + wid;
  float* w = TV + (size_t)row * E_;
  float4 v[4];
  #pragma unroll
  for (int j = 0; j < 4; j++) v[j] = ((float4*)w)[lane + 64 * j];
  float s = 0.f;
  #pragma unroll
  for (int j = 0; j < 4; j++)
    s += v[j].x * v[j].x + v[j].y * v[j].y + v[j].z * v[j].z + v[j].w * v[j].w;
  #pragma unroll
  for (int m = 1; m < 64; m <<= 1) s += __shfl_xor(s, m, 64);
  float n = sqrtf(fmaxf(s, 1e-15f));
  float f = tanhf(n) / n;
  #pragma unroll
  for (int j = 0; j < 4; j++) {
    v[j].x *= f; v[j].y *= f; v[j].z *= f; v[j].w *= f;
    ((float4*)w)[lane + 64 * j] = v[j];
  }
}

extern "C" void kernel_launch(void* const* d_in, const int* in_sizes, int n_in,
                              void* d_out, int out_size, void* d_ws, size_t ws_size,
                              hipStream_t stream) {
  (void)in_sizes; (void)n_in; (void)out_size; (void)ws_size;
  const float* q  = (const float*)d_in[0];
  const float* k  = (const float*)d_in[1];
  const float* v  = (const float*)d_in[2];
  const float* zq = (const float*)d_in[3];
  const float* bq = (const float*)d_in[4];
  const float* zk = (const float*)d_in[5];
  const float* bk = (const float*)d_in[6];
  const float* zv = (const float*)d_in[7];
  const float* bv = (const float*)d_in[8];

  unsigned short* Wbf = (unsigned short*)d_ws;                       // 3*BS*E bf16 (25.2 MB)
  unsigned short* Pbf = Wbf + (size_t)3 * BS_ * E_;                  // 3*BS*E bf16 (25.2 MB)
  unsigned short* BhiT = Pbf;                                        // aliases Pbf (dead until normalize)
  unsigned short* Xbf = Pbf + (size_t)3 * BS_ * E_;                  // 3*BS*E bf16 (25.2 MB)
  float* HN           = (float*)(Xbf + (size_t)3 * BS_ * E_);        // BS*16 fp32 (q only)
  float* lamRow       = HN + (size_t)3 * BS_ * H_;
  float* Zpart        = lamRow + 3 * BS_;                            // 3*16*1024 fp32 (196 KB)
  unsigned short* VtG = (unsigned short*)(Zpart + 48 * E_);          // B*H*64*S bf16 (8.4 MB)
  unsigned short* KsG = VtG + (size_t)B_ * H_ * 64 * S_;             // B*H*S*64 bf16 (8.4 MB)
  unsigned short* lamMG = KsG + (size_t)B_ * H_ * S_ * 64;           // B*H*S bf16 (128 KB)
  unsigned int* auxG  = (unsigned int*)(lamMG + (size_t)B_ * H_ * S_); // B*H*S uint (256 KB)
  unsigned short* PvF = Pbf + (size_t)2 * BS_ * E_;                  // lambda-folded v rows (mat2 slot)
  float* out          = (float*)d_out;

  double lb1 = lgamma(E_ / 2.0) + lgamma(0.5) - lgamma(E_ / 2.0 + 0.5);
  double lb2 = lgamma(D_ / 2.0) + lgamma(0.5) - lgamma(D_ / 2.0 + 0.5);
  float scale = (float)exp(lb1 - lb2);

  hipLaunchKernelGGL(prep_kernel, dim3(3 * BS_ / 4 + 768), dim3(256), 0, stream,
                     q, k, v, Xbf, lamRow, zq, zk, zv, BhiT, Zpart);
  hipLaunchKernelGGL(hlinear_mfma_kernel, dim3(768), dim3(256), 0, stream,
                     Xbf, BhiT, lamRow, Zpart, bq, bk, bv, Wbf);
  hipLaunchKernelGGL(normalize_kernel, dim3(3 * BS_ / 4), dim3(256), 0, stream,
                     Wbf, Pbf, HN, KsG, lamMG, auxG);
  hipLaunchKernelGGL(vtrans_kernel, dim3(16, 16, 4), dim3(256), 0, stream, PvF, VtG);
  hipLaunchKernelGGL(attention_kernel, dim3(512), dim3(512), 0, stream,
                     Pbf, HN, KsG, VtG, lamMG, auxG, out, scale);
  hipLaunchKernelGGL(expmap_kernel, dim3(BS_ / 4), dim3(256), 0, stream, out);
}

// Round 8
// 212.940 us; speedup vs baseline: 1.0210x; 1.0210x over previous
//
#include <hip/hip_runtime.h>
#include <cmath>

#define EPSF 1e-7f

constexpr int B_ = 4, S_ = 1024, E_ = 1024, H_ = 16, D_ = 64;
constexpr int BS_ = B_ * S_;   // 4096 rows per matrix

typedef __attribute__((ext_vector_type(8))) short bf16x8;
typedef __attribute__((ext_vector_type(4))) float f32x4;

__device__ inline unsigned int fbits(float f) { union { float f; unsigned int u; } x; x.f = f; return x.u; }
__device__ inline float ubits(unsigned int u) { union { unsigned int u; float f; } x; x.u = u; return x.f; }

__device__ inline unsigned short f2bf(float f) {
  unsigned int u = fbits(f);
  unsigned int r = u + 0x7fffu + ((u >> 16) & 1u);   // RNE
  return (unsigned short)(r >> 16);
}
__device__ inline float bf2f(unsigned short h) { return ubits(((unsigned int)h) << 16); }
__device__ inline float fastrcp(float x) { return __builtin_amdgcn_rcpf(x); }
__device__ inline float fastsqrt(float x) { return __builtin_amdgcn_sqrtf(x); }

// async global -> LDS DMA, 16B/lane; LDS dest = wave-uniform base + lane*16
__device__ __forceinline__ void async_ld16(const unsigned short* g, unsigned short* l) {
  __builtin_amdgcn_global_load_lds(
      (const __attribute__((address_space(1))) unsigned int*)g,
      (__attribute__((address_space(3))) unsigned int*)l, 16, 0, 0);
}

// pack two f32 -> one u32 of 2 bf16 (RNE), single VALU op
__device__ __forceinline__ unsigned int cvt_pk_bf16(float lo, float hi) {
  unsigned int r;
  asm("v_cvt_pk_bf16_f32 %0, %1, %2" : "=v"(r) : "v"(lo), "v"(hi));
  return r;
}
// a.rows{2,3} <-> b.rows{0,1}
__device__ __forceinline__ void permlane32_swap(unsigned int &a, unsigned int &b) {
  asm("v_permlane32_swap_b32 %0, %1" : "+v"(a), "+v"(b));
}
// a.rows{1,3} <-> b.rows{0,2}
__device__ __forceinline__ void permlane16_swap(unsigned int &a, unsigned int &b) {
  asm("v_permlane16_swap_b32 %0, %1" : "+v"(a), "+v"(b));
}

// ---------------- kernel 1: fused prep ----------------
// blocks [0, 3*BS/4): x -> RNE bf16 + per-row lambda, one WAVE per row (no LDS/barrier)
// blocks [3*BS/4, +768): transpose z -> RNE bf16 BT[n][k] + partial column sums (zsplit)
__global__ __launch_bounds__(256) void prep_kernel(
    const float* __restrict__ xq, const float* __restrict__ xk,
    const float* __restrict__ xv, unsigned short* __restrict__ Xbf,
    float* __restrict__ lamRow,
    const float* __restrict__ zq, const float* __restrict__ zk, const float* __restrict__ zv,
    unsigned short* __restrict__ BhiT, float* __restrict__ Zpart) {
  const int bid = blockIdx.x;
  const int tid = threadIdx.x;
  if (bid < 3 * BS_ / 4) {
    // ---- xsplit: wave-per-row ----
    const int wid = tid >> 6, lane = tid & 63;
    const int row = bid * 4 + wid;
    const float* x = (row < BS_) ? xq : (row < 2 * BS_ ? xk : xv);
    const int r = row & (BS_ - 1);
    const float4* src = (const float4*)(x + (size_t)r * E_);
    float4 v[4];
    #pragma unroll
    for (int j = 0; j < 4; j++) v[j] = src[lane + 64 * j];
    float s = 0.f;
    #pragma unroll
    for (int j = 0; j < 4; j++)
      s += v[j].x * v[j].x + v[j].y * v[j].y + v[j].z * v[j].z + v[j].w * v[j].w;
    #pragma unroll
    for (int m = 1; m < 64; m <<= 1) s += __shfl_xor(s, m, 64);
    uint2* dst = (uint2*)(Xbf + (size_t)row * E_);
    #pragma unroll
    for (int j = 0; j < 4; j++) {
      uint2 p;
      p.x = (unsigned int)f2bf(v[j].x) | ((unsigned int)f2bf(v[j].y) << 16);
      p.y = (unsigned int)f2bf(v[j].z) | ((unsigned int)f2bf(v[j].w) << 16);
      dst[lane + 64 * j] = p;
    }
    if (lane == 0) lamRow[row] = 2.0f / fmaxf(1.0f - s, EPSF);
    return;
  }
  // ---- zsplit ----
  const int lid = bid - 3 * BS_ / 4;           // 0..767
  const int mat = lid >> 8;                    // 0..2
  const int rem = lid & 255;
  const int ky = rem >> 4, nx = rem & 15;
  const float* z = mat == 0 ? zq : (mat == 1 ? zk : zv);
  const int k0 = ky * 64, n0 = nx * 64;
  __shared__ float t[64][65];
  __shared__ float sred[64][4];
  {
    int kr = tid >> 4, nc = (tid & 15) * 4;
    #pragma unroll
    for (int i = 0; i < 4; i++) {
      float4 vv = *(const float4*)(z + (size_t)(k0 + kr + i * 16) * E_ + n0 + nc);
      t[kr + i * 16][nc + 0] = vv.x;
      t[kr + i * 16][nc + 1] = vv.y;
      t[kr + i * 16][nc + 2] = vv.z;
      t[kr + i * 16][nc + 3] = vv.w;
    }
  }
  __syncthreads();
  int nr = tid >> 2, kc = (tid & 3) * 16;
  unsigned int ph[8];
  float ss = 0.f;
  #pragma unroll
  for (int p = 0; p < 8; p++) {
    float x0 = t[kc + 2 * p][nr], x1 = t[kc + 2 * p + 1][nr];
    ph[p] = (unsigned int)f2bf(x0) | ((unsigned int)f2bf(x1) << 16);
    ss += x0 * x0 + x1 * x1;
  }
  size_t off = (size_t)mat * E_ * E_ + (size_t)(n0 + nr) * E_ + k0 + kc;
  uint4* dh = (uint4*)(BhiT + off);
  dh[0] = make_uint4(ph[0], ph[1], ph[2], ph[3]);
  dh[1] = make_uint4(ph[4], ph[5], ph[6], ph[7]);
  sred[nr][tid & 3] = ss;
  __syncthreads();
  if (tid < 64) {
    float v = sred[tid][0] + sred[tid][1] + sred[tid][2] + sred[tid][3];
    Zpart[(size_t)(mat * 16 + ky) * E_ + n0 + tid] = v;
  }
}

// ---------------- kernel 3: 1-term bf16 MFMA GEMM, (mat,m0)-pairs per XCD, zstat folded ----------------
// REVERTED to the round-5 structure: 2 barriers/K-step, 36 KB LDS, 3 blocks/CU.  The round-7
// double-buffer pipeline (67 KB LDS, 2 blocks/CU) regressed 48->55: at 12 waves/CU the implicit
// cross-block wave overlap already hides staging latency; the occupancy loss dominated (m114/m132).
// Keeps the (mat,m0)-per-XCD grouping (A-panel L2-shared: FETCH 102 -> 30 MB, verified r7).
__global__ __launch_bounds__(256, 3) void hlinear_mfma_kernel(
    const unsigned short* __restrict__ Xbf,
    const unsigned short* __restrict__ BhiT,
    const float* __restrict__ lamRow, const float* __restrict__ Zpart,
    const float* __restrict__ bq, const float* __restrict__ bk, const float* __restrict__ bv,
    unsigned short* __restrict__ Wbf) {
  const int fid = blockIdx.x;
  const int xcd = fid & 7, j = fid >> 3;
  const int n0 = (j & 7) * 128;
  const int gp = xcd * 12 + (j >> 3);   // 0..95
  const int mat = gp >> 5;
  const int m0 = (gp & 31) * 128;

  const unsigned short* xa = Xbf + (size_t)mat * BS_ * E_;
  const unsigned short* bh = BhiT + (size_t)mat * E_ * E_;

  __shared__ unsigned short LDSU[18432];   // 36864 B; staging (As,Bh) + epilogue reuse
  __shared__ float chznS[128], shS[128], tznS[128];
  unsigned short* As = LDSU;               // 128 rows x 64 shorts
  unsigned short* Bh = LDSU + 8192;

  const int tid = threadIdx.x;
  const int wid = tid >> 6, lane = tid & 63, quad = lane >> 4, l16 = lane & 15;
  const int wm = (wid >> 1) * 64, wn = (wid & 1) * 64;

  // ---- prologue: column stats (zstat fold) ----
  if (tid < 128) {
    const int col = n0 + tid;
    float s = 0.f;
    #pragma unroll
    for (int ky = 0; ky < 16; ky++)
      s += Zpart[(size_t)(mat * 16 + ky) * E_ + col];
    float zn = fmaxf(sqrtf(s), 1e-15f);
    const float* bb = (mat == 0) ? bq : ((mat == 1) ? bk : bv);
    float rb = bb[col];
    chznS[tid] = coshf(2.f * rb) / zn;
    shS[tid] = sinhf(2.f * rb);
    tznS[tid] = 2.f * zn;
  }

  f32x4 acc[4][4];
  #pragma unroll
  for (int i = 0; i < 4; i++)
    #pragma unroll
    for (int jj = 0; jj < 4; jj++) acc[i][jj] = (f32x4){0.f, 0.f, 0.f, 0.f};

  const int lrow = lane >> 3;
  const int lcs = ((lane & 7) ^ lrow) * 8;
  const int xsw = (l16 & 7);

  for (int kt = 0; kt < E_ / 64; ++kt) {
    __syncthreads();
    const int kb = kt * 64 + lcs;
    #pragma unroll
    for (int c2 = 0; c2 < 4; c2++) {
      const int c = wid * 4 + c2;
      const int grow = c * 8 + lrow;
      async_ld16(xa + (size_t)(m0 + grow) * E_ + kb, As + c * 512);
      async_ld16(bh + (size_t)(n0 + grow) * E_ + kb, Bh + c * 512);
    }
    __syncthreads();
    #pragma unroll
    for (int h = 0; h < 2; h++) {
      bf16x8 a[4];
      #pragma unroll
      for (int mt = 0; mt < 4; mt++) {
        int row = wm + mt * 16 + l16;
        a[mt] = *(const bf16x8*)&As[row * 64 + (((h * 4 + quad) ^ xsw) * 8)];
      }
      #pragma unroll
      for (int nt = 0; nt < 4; nt++) {
        int row = wn + nt * 16 + l16;
        bf16x8 bhf = *(const bf16x8*)&Bh[row * 64 + (((h * 4 + quad) ^ xsw) * 8)];
        #pragma unroll
        for (int mt = 0; mt < 4; mt++)
          acc[mt][nt] = __builtin_amdgcn_mfma_f32_16x16x32_bf16(a[mt], bhf, acc[mt][nt], 0, 0, 0);
      }
    }
  }

  const float* lamP = lamRow + mat * BS_;
  float lamv[16];
  #pragma unroll
  for (int mt = 0; mt < 4; mt++)
    #pragma unroll
    for (int r = 0; r < 4; r++)
      lamv[mt * 4 + r] = lamP[m0 + wm + mt * 16 + quad * 4 + r];

  __syncthreads();
  unsigned short* epi = LDSU + wid * 4608;   // 64 rows x 72 shorts
  #pragma unroll
  for (int nt = 0; nt < 4; nt++) {
    int ci = wn + nt * 16 + l16;
    float chzn = chznS[ci];
    float sh = shS[ci];
    float tzn = tznS[ci];
    #pragma unroll
    for (int mt = 0; mt < 4; mt++) {
      #pragma unroll
      for (int r = 0; r < 4; r++) {
        float lam = lamv[mt * 4 + r];
        float arg = fmaf(lam * acc[mt][nt][r], chzn, -(lam - 1.f) * sh);
        float sq2 = sqrtf(fmaf(arg, arg, 1.f));
        float v = tzn * __logf(arg + sq2);
        float ev = __expf(v);
        float w = 0.5f * (ev - fastrcp(ev));
        epi[(mt * 16 + quad * 4 + r) * 72 + nt * 16 + l16] = f2bf(w);
      }
    }
  }
  unsigned short* gout = Wbf + (size_t)mat * BS_ * E_ + (size_t)(m0 + wm) * E_ + n0 + wn;
  const int rrow = lane >> 3, seg = lane & 7;
  #pragma unroll
  for (int i = 0; i < 8; i++) {
    int row = i * 8 + rrow;
    uint4 val = *(const uint4*)&epi[row * 72 + seg * 8];
    *(uint4*)(gout + (size_t)row * E_ + seg * 8) = val;
  }
}

// ---------------- kernel 4: MERGED normalize (q,k) + v-normalize/head-transpose ----------------
// blocks [0, 2*BS/4): wave-per-row normalize for q,k rows (unchanged math).
// blocks [2*BS/4, +1024): v-path, SELF-SUFFICIENT (reads Wbf v-rows, recomputes full-row norms
// with the identical 64-lane butterfly, then per-key head-norm/lam with identical rounding) and
// writes the lambda-folded V^T + lamM.  The 16 head-blocks of each (b,st) are pinned to one XCD
// so the full-row re-reads are L2-hits.  Replaces the normalize-mat2 path, the PvF buffer, and
// the separate vtrans launch (6 -> 5 kernels).
__global__ __launch_bounds__(256) void norm_vtrans_kernel(
    const unsigned short* __restrict__ Wbf, unsigned short* __restrict__ Pbf,
    float* __restrict__ HN,
    unsigned short* __restrict__ KsG, unsigned short* __restrict__ lamMG,
    unsigned int* __restrict__ auxG, unsigned short* __restrict__ VtG) {
  const int bid = blockIdx.x;
  const int tid = threadIdx.x;
  if (bid < 2 * BS_ / 4) {
    // ---- normalize q,k rows (wave-per-row) ----
    const int wid = tid >> 6, lane = tid & 63;
    const int row = bid * 4 + wid;               // 0 .. 2*BS-1
    const unsigned short* w = Wbf + (size_t)row * E_;
    union { uint4 q[2]; unsigned short s[16]; } in;
    in.q[0] = ((const uint4*)w)[lane * 2];
    in.q[1] = ((const uint4*)w)[lane * 2 + 1];
    float wv[16];
    float s = 0.f;
    #pragma unroll
    for (int i = 0; i < 16; i++) { wv[i] = bf2f(in.s[i]); s += wv[i] * wv[i]; }
    #pragma unroll
    for (int m = 1; m < 64; m <<= 1) s += __shfl_xor(s, m, 64);
    float t = 1.f / (1.f + sqrtf(1.f + s));
    union { uint4 q[2]; unsigned short s[16]; } out;
    float rv[16];
    float hs = 0.f;
    #pragma unroll
    for (int i = 0; i < 16; i++) {
      unsigned short p = f2bf(wv[i] * t);
      out.s[i] = p;
      rv[i] = bf2f(p);
      hs += rv[i] * rv[i];
    }
    hs += __shfl_xor(hs, 1, 64);
    hs += __shfl_xor(hs, 2, 64);                 // per-head (4-lane group) squared norm
    const int mat = row >= BS_ ? 1 : 0;
    const int r4 = row & (BS_ - 1);
    const int b = r4 >> 10, key = r4 & (S_ - 1);
    const int head = lane >> 2;
    const size_t bhS = ((size_t)(b * H_ + head)) * S_;
    if (mat == 0) {
      ((uint4*)(Pbf + (size_t)row * E_))[lane * 2] = out.q[0];
      ((uint4*)(Pbf + (size_t)row * E_))[lane * 2 + 1] = out.q[1];
      if ((lane & 3) == 0) HN[(size_t)r4 * H_ + head] = hs;
    } else {
      float c = fastrcp(1.f - hs);
      union { uint4 q[2]; unsigned short s[16]; } ks;
      #pragma unroll
      for (int i = 0; i < 16; i++) ks.s[i] = f2bf(rv[i] * c);
      unsigned short* dst = KsG + (bhS + key) * 64 + (lane & 3) * 16;
      ((uint4*)dst)[0] = ks.q[0];
      ((uint4*)dst)[1] = ks.q[1];
      if ((lane & 3) == 0)
        auxG[bhS + key] = (unsigned int)f2bf(c) | ((unsigned int)f2bf(c * hs) << 16);
    }
    return;
  }
  // ---- v-path: (st,h,b) tile, XCD-grouped so the 16 h-blocks of one (b,st) share row reads ----
  const int lid = bid - 2 * BS_ / 4;             // 0..1023; global fid = 2048+lid, 2048%8==0
  const int xcd = lid & 7, s2 = lid >> 3;        // s2 0..127
  const int g = xcd + 8 * (s2 >> 4);             // 0..63 = b*16+st group
  const int h = s2 & 15;
  const int b = g >> 4, st = g & 15;
  const unsigned short* wvbase = Wbf + (size_t)2 * BS_ * E_;
  __shared__ unsigned short T[64][72];
  __shared__ float tS[64];
  const int wid = tid >> 6, lane = tid & 63;
  // phase 1: per-key full-row norm (identical butterfly), stash head-h slice in LDS
  #pragma unroll 1
  for (int kk = 0; kk < 16; ++kk) {
    const int key = wid * 16 + kk;
    const unsigned short* rowp = wvbase + (size_t)(b * S_ + st * 64 + key) * E_;
    union { uint4 q[2]; unsigned short s[16]; } in;
    in.q[0] = ((const uint4*)rowp)[lane * 2];
    in.q[1] = ((const uint4*)rowp)[lane * 2 + 1];
    float s = 0.f;
    #pragma unroll
    for (int i = 0; i < 16; i++) { float f = bf2f(in.s[i]); s += f * f; }
    #pragma unroll
    for (int m = 1; m < 64; m <<= 1) s += __shfl_xor(s, m, 64);
    if ((lane >> 2) == h) {                      // lanes 4h..4h+3 hold head h's 64 dims
      *(uint4*)&T[key][(lane & 3) * 16] = in.q[0];
      *(uint4*)&T[key][(lane & 3) * 16 + 8] = in.q[1];
    }
    if (lane == 0) tS[key] = 1.f / (1.f + sqrtf(1.f + s));
  }
  __syncthreads();
  // phase 2: per-key head-norm hs (identical per-lane order + 4-lane shfl), lam, fold into T
  {
    const int kr = tid >> 2, lc = (tid & 3) * 16;
    const float t = tS[kr];
    float rv[16];
    float hp = 0.f;
    #pragma unroll
    for (int i = 0; i < 16; i++) {
      unsigned short p = f2bf(bf2f(T[kr][lc + i]) * t);
      rv[i] = bf2f(p);
      hp += rv[i] * rv[i];
    }
    hp += __shfl_xor(hp, 1, 64);
    hp += __shfl_xor(hp, 2, 64);
    float lam = 2.f / fmaxf(1.f - hp, EPSF);
    #pragma unroll
    for (int i = 0; i < 16; i++) T[kr][lc + i] = f2bf(rv[i] * lam);
    const size_t bhS = ((size_t)(b * H_ + h)) * S_;
    if ((tid & 3) == 0) lamMG[bhS + st * 64 + kr] = f2bf(lam - 1.f);
  }
  __syncthreads();
  // phase 3: transposed write (exact old vtrans pattern)
  {
    const int d = tid >> 2, sc = (tid & 3) * 16;
    unsigned int o[8];
    #pragma unroll
    for (int i = 0; i < 8; i++) {
      int s0 = sc + 2 * i;
      o[i] = (unsigned int)T[s0][d] | ((unsigned int)T[s0 + 1][d] << 16);
    }
    const size_t bhS = ((size_t)(b * H_ + h)) * S_;
    unsigned short* dst = VtG + bhS * 64 + (size_t)d * S_ + st * 64 + sc;
    ((uint4*)dst)[0] = make_uint4(o[0], o[1], o[2], o[3]);
    ((uint4*)dst)[1] = make_uint4(o[4], o[5], o[6], o[7]);
  }
}

// ---------------- kernel 5: MFMA attention; XCD-grouped, BK=128 double-tile pipeline ----------------
// (round-5 version: 512 thr / 8 waves, 16 waves/CU.)
__global__ __launch_bounds__(512) void attention_kernel(
    const unsigned short* __restrict__ Pbf, const float* __restrict__ HN,
    const unsigned short* __restrict__ KsG, const unsigned short* __restrict__ VtG,
    const unsigned short* __restrict__ lamMG, const unsigned int* __restrict__ auxG,
    float* __restrict__ TV, float scale) {
  const int fid = blockIdx.x;
  const int xcd = fid & 7, slot = fid >> 3;          // slot 0..63
  const int group = xcd + 8 * (slot >> 3);           // 0..63  (= h + 16*b)
  const int qt = slot & 7;
  const int h = group & 15, b = group >> 4;

  const unsigned short* pq = Pbf;
  const float* hnq = HN;

  const int tid = threadIdx.x;
  const int wid = tid >> 6, lane = tid & 63;
  const int quad = lane >> 4, l16 = lane & 15;

  __shared__ __align__(16) unsigned short Kl[2][8192];   // 2 x (2 key-tiles x 64x64), xor-swizzled
  __shared__ __align__(16) unsigned short Vl[2][8192];   // 2 x (2 dim-tiles), xor-swizzled
  __shared__ __align__(16) unsigned short lamL[1024];
  __shared__ __align__(16) unsigned int auxL[1024];

  const size_t bhS = (size_t)(b * H_ + h) * S_;
  const int lr = lane >> 3, cch = lane & 7;
  const int xsw = l16 & 7;
  const unsigned short* kbase = KsG + bhS * 64;   // row stride 64
  const unsigned short* vbase = VtG + bhS * 64;
  const int srow = wid * 8 + lr;                  // staging row (K: key / V: dim)
  const int scc = ((cch ^ lr) * 8);               // pre-swizzled source column

  // stage super-tile 0 (key tiles 0,1) early (latency overlaps Q prep)
  async_ld16(kbase + (size_t)srow * 64 + scc, &Kl[0][wid * 512]);
  async_ld16(kbase + (size_t)(64 + srow) * 64 + scc, &Kl[0][4096 + wid * 512]);
  async_ld16(vbase + (size_t)srow * S_ + scc, &Vl[0][wid * 512]);
  async_ld16(vbase + (size_t)srow * S_ + 64 + scc, &Vl[0][4096 + wid * 512]);

  ((unsigned int*)lamL)[tid] = ((const unsigned int*)(lamMG + bhS))[tid];
  ((uint2*)auxL)[tid] = ((const uint2*)(auxG + bhS))[tid];

  const int qrow0 = qt * 128 + wid * 16;
  const size_t qgrow = ((size_t)(b * S_ + qrow0 + l16)) * E_ + h * 64;
  bf16x8 aq0r = *(const bf16x8*)(pq + qgrow + quad * 8);
  bf16x8 aq1r = *(const bf16x8*)(pq + qgrow + 32 + quad * 8);
  const float q2l = hnq[((size_t)(b * S_ + qrow0 + l16)) * H_ + h];
  const float al = 2.f * fastrcp(1.f - q2l);
  const float sc2 = -2.f * al;
  bf16x8 aq0, aq1;
  #pragma unroll
  for (int j = 0; j < 8; j++) {
    aq0[j] = (short)f2bf(bf2f((unsigned short)aq0r[j]) * sc2);
    aq1[j] = (short)f2bf(bf2f((unsigned short)aq1r[j]) * sc2);
  }
  const unsigned short ae0 = (quad == 0) ? f2bf(al * q2l) : 0;
  const unsigned short ae1 = (quad == 0) ? f2bf(al) : 0;
  const bf16x8 aex = (bf16x8){(short)ae0, (short)ae1, 0, 0, 0, 0, 0, 0};

  f32x4 accO[4];
  #pragma unroll
  for (int dt = 0; dt < 4; dt++) accO[dt] = (f32x4){0.f, 0.f, 0.f, 0.f};
  f32x4 accD = (f32x4){0.f, 0.f, 0.f, 0.f};

  // prologue drain: super-tile 0 + lam/aux all complete
  asm volatile("s_waitcnt vmcnt(0) lgkmcnt(0)" ::: "memory");
  __builtin_amdgcn_s_barrier();

  const int NIT = S_ / 128;   // 8
  int buf = 0;
  #pragma unroll 1
  for (int it = 0; it < NIT; ++it) {
    if (it + 1 < NIT) {   // stage next super-tile early; lands during this 2-tile compute
      const int kr0 = (it + 1) * 128;
      async_ld16(kbase + (size_t)(kr0 + srow) * 64 + scc, &Kl[buf ^ 1][wid * 512]);
      async_ld16(kbase + (size_t)(kr0 + 64 + srow) * 64 + scc, &Kl[buf ^ 1][4096 + wid * 512]);
      async_ld16(vbase + (size_t)srow * S_ + kr0 + scc, &Vl[buf ^ 1][wid * 512]);
      async_ld16(vbase + (size_t)srow * S_ + kr0 + 64 + scc, &Vl[buf ^ 1][4096 + wid * 512]);
    }
    #pragma unroll
    for (int half = 0; half < 2; half++) {
      const int kt = it * 2 + half;
      const unsigned short* Kb = &Kl[buf][half * 4096];
      const unsigned short* Vb = &Vl[buf][half * 4096];

      // ---- scores (swapped): per lane q=l16, key=16nt+4quad+r2; w = A - sqrt(A^2-1) ----
      unsigned int Wp[4][2];
      #pragma unroll
      for (int nt = 0; nt < 4; nt++) {
        const int krow = nt * 16 + l16;
        bf16x8 bk0 = *(const bf16x8*)&Kb[krow * 64 + ((quad ^ xsw) * 8)];
        bf16x8 bk1 = *(const bf16x8*)&Kb[krow * 64 + (((4 + quad) ^ xsw) * 8)];
        unsigned int av = (quad == 0) ? auxL[kt * 64 + krow] : 0u;
        bf16x8 bex = (bf16x8){(short)(av & 0xFFFF), (short)(av >> 16), 0, 0, 0, 0, 0, 0};
        f32x4 z = (f32x4){0.f, 0.f, 0.f, 0.f};
        f32x4 st = __builtin_amdgcn_mfma_f32_16x16x32_bf16(bex, aex, z, 0, 0, 0);
        st = __builtin_amdgcn_mfma_f32_16x16x32_bf16(bk0, aq0, st, 0, 0, 0);
        st = __builtin_amdgcn_mfma_f32_16x16x32_bf16(bk1, aq1, st, 0, 0, 0);
        float w[4];
        #pragma unroll
        for (int r2 = 0; r2 < 4; r2++) {
          float t = fmaxf(st[r2], 1e-6f);
          float A = 1.f + t;
          w[r2] = A - fastsqrt(fmaf(A, A, -1.f));
        }
        Wp[nt][0] = cvt_pk_bf16(w[0], w[1]);
        Wp[nt][1] = cvt_pk_bf16(w[2], w[3]);
      }
      // ---- redistribute scores into PV A-fragments (registers only) ----
      unsigned int x00 = Wp[0][0], y00 = Wp[1][0];
      permlane32_swap(x00, y00); permlane16_swap(x00, y00);
      unsigned int x01 = Wp[0][1], y01 = Wp[1][1];
      permlane32_swap(x01, y01); permlane16_swap(x01, y01);
      unsigned int x10 = Wp[2][0], y10 = Wp[3][0];
      permlane32_swap(x10, y10); permlane16_swap(x10, y10);
      unsigned int x11 = Wp[2][1], y11 = Wp[3][1];
      permlane32_swap(x11, y11); permlane16_swap(x11, y11);
      union { unsigned int u[4]; bf16x8 v; } ap0u, ap1u;
      ap0u.u[0] = x00; ap0u.u[1] = x01; ap0u.u[2] = y00; ap0u.u[3] = y01;
      ap1u.u[0] = x10; ap1u.u[1] = x11; ap1u.u[2] = y10; ap1u.u[3] = y11;
      const bf16x8 ap0 = ap0u.v, ap1 = ap1u.v;

      // ---- PV + dnm via K=32 MFMA ----
      #pragma unroll
      for (int dt = 0; dt < 4; dt++) {
        const int drow = dt * 16 + l16;
        bf16x8 bv0 = *(const bf16x8*)&Vb[drow * 64 + ((quad ^ xsw) * 8)];
        bf16x8 bv1 = *(const bf16x8*)&Vb[drow * 64 + (((4 + quad) ^ xsw) * 8)];
        accO[dt] = __builtin_amdgcn_mfma_f32_16x16x32_bf16(ap0, bv0, accO[dt], 0, 0, 0);
        accO[dt] = __builtin_amdgcn_mfma_f32_16x16x32_bf16(ap1, bv1, accO[dt], 0, 0, 0);
      }
      bf16x8 bl0 = *(const bf16x8*)&lamL[kt * 64 + quad * 8];        // broadcast per quad
      bf16x8 bl1 = *(const bf16x8*)&lamL[kt * 64 + 32 + quad * 8];
      accD = __builtin_amdgcn_mfma_f32_16x16x32_bf16(ap0, bl0, accD, 0, 0, 0);
      accD = __builtin_amdgcn_mfma_f32_16x16x32_bf16(ap1, bl1, accD, 0, 0, 0);
    }

    // next super-tile staged early has had the whole 2-tile compute to land
    asm volatile("s_waitcnt vmcnt(0)" ::: "memory");
    __builtin_amdgcn_s_barrier();
    buf ^= 1;
  }

  // ---- finalize: u = num/dnm; midpoint; logmap0*scale ----
  #pragma unroll
  for (int r2 = 0; r2 < 4; r2++) {
    float rdsum = fastrcp(accD[r2]);                 // dnm >= 1 (lam-1 >= 1)
    float uu[4];
    float su = 0.f;
    #pragma unroll
    for (int dt = 0; dt < 4; dt++) { uu[dt] = accO[dt][r2] * rdsum; su += uu[dt] * uu[dt]; }
    su += __shfl_xor(su, 1, 64);
    su += __shfl_xor(su, 2, 64);
    su += __shfl_xor(su, 4, 64);
    su += __shfl_xor(su, 8, 64);
    float g = fastrcp(1.f + fastsqrt(fmaxf(1.f - su, EPSF)));
    float n2 = fmaxf(su * g * g, 1e-15f);
    float n = fastsqrt(n2);
    float fac = atanhf(fminf(n, 1.f - 1e-6f)) * fastrcp(n) * g * scale;
    size_t orow = ((size_t)(b * S_ + qrow0 + quad * 4 + r2)) * E_ + h * 64 + l16;
    #pragma unroll
    for (int dt = 0; dt < 4; dt++) TV[orow + dt * 16] = fac * uu[dt];
  }
}

// ---------------- kernel 6: expmap0 per full E-row, in-place on d_out (wave-per-row) ----------------
__global__ __launch_bounds__(256) void expmap_kernel(float* __restrict__ TV) {
  const int wid = threadIdx.x >> 6, lane = threadIdx.x & 63;
  const int row = blockIdx.x * 4 + wid;
  float* w = TV + (size_t)row * E_;
  float4 v[4];
  #pragma unroll
  for (int j = 0; j < 4; j++) v[j] = ((float4*)w)[lane + 64 * j];
  float s = 0.f;
  #pragma unroll
  for (int j = 0; j < 4; j++)
    s += v[j].x * v[j].x + v[j].y * v[j].y + v[j].z * v[j].z + v[j].w * v[j].w;
  #pragma unroll
  for (int m = 1; m < 64; m <<= 1) s += __shfl_xor(s, m, 64);
  float n = sqrtf(fmaxf(s, 1e-15f));
  float f = tanhf(n) / n;
  #pragma unroll
  for (int j = 0; j < 4; j++) {
    v[j].x *= f; v[j].y *= f; v[j].z *= f; v[j].w *= f;
    ((float4*)w)[lane + 64 * j] = v[j];
  }
}

extern "C" void kernel_launch(void* const* d_in, const int* in_sizes, int n_in,
                              void* d_out, int out_size, void* d_ws, size_t ws_size,
                              hipStream_t stream) {
  (void)in_sizes; (void)n_in; (void)out_size; (void)ws_size;
  const float* q  = (const float*)d_in[0];
  const float* k  = (const float*)d_in[1];
  const float* v  = (const float*)d_in[2];
  const float* zq = (const float*)d_in[3];
  const float* bq = (const float*)d_in[4];
  const float* zk = (const float*)d_in[5];
  const float* bk = (const float*)d_in[6];
  const float* zv = (const float*)d_in[7];
  const float* bv = (const float*)d_in[8];

  unsigned short* Wbf = (unsigned short*)d_ws;                       // 3*BS*E bf16 (25.2 MB)
  unsigned short* Pbf = Wbf + (size_t)3 * BS_ * E_;                  // 3*BS*E bf16 (25.2 MB)
  unsigned short* BhiT = Pbf;                                        // aliases Pbf (dead until normalize)
  unsigned short* Xbf = Pbf + (size_t)3 * BS_ * E_;                  // 3*BS*E bf16 (25.2 MB)
  float* HN           = (float*)(Xbf + (size_t)3 * BS_ * E_);        // BS*16 fp32 (q only)
  float* lamRow       = HN + (size_t)3 * BS_ * H_;
  float* Zpart        = lamRow + 3 * BS_;                            // 3*16*1024 fp32 (196 KB)
  unsigned short* VtG = (unsigned short*)(Zpart + 48 * E_);          // B*H*64*S bf16 (8.4 MB)
  unsigned short* KsG = VtG + (size_t)B_ * H_ * 64 * S_;             // B*H*S*64 bf16 (8.4 MB)
  unsigned short* lamMG = KsG + (size_t)B_ * H_ * S_ * 64;           // B*H*S bf16 (128 KB)
  unsigned int* auxG  = (unsigned int*)(lamMG + (size_t)B_ * H_ * S_); // B*H*S uint (256 KB)
  float* out          = (float*)d_out;

  double lb1 = lgamma(E_ / 2.0) + lgamma(0.5) - lgamma(E_ / 2.0 + 0.5);
  double lb2 = lgamma(D_ / 2.0) + lgamma(0.5) - lgamma(D_ / 2.0 + 0.5);
  float scale = (float)exp(lb1 - lb2);

  hipLaunchKernelGGL(prep_kernel, dim3(3 * BS_ / 4 + 768), dim3(256), 0, stream,
                     q, k, v, Xbf, lamRow, zq, zk, zv, BhiT, Zpart);
  hipLaunchKernelGGL(hlinear_mfma_kernel, dim3(768), dim3(256), 0, stream,
                     Xbf, BhiT, lamRow, Zpart, bq, bk, bv, Wbf);
  hipLaunchKernelGGL(norm_vtrans_kernel, dim3(2 * BS_ / 4 + 1024), dim3(256), 0, stream,
                     Wbf, Pbf, HN, KsG, lamMG, auxG, VtG);
  hipLaunchKernelGGL(attention_kernel, dim3(512), dim3(512), 0, stream,
                     Pbf, HN, KsG, VtG, lamMG, auxG, out, scale);
  hipLaunchKernelGGL(expmap_kernel, dim3(BS_ / 4), dim3(256), 0, stream, out);
}